// Round 2
// baseline (192.281 us; speedup 1.0000x reference)
//
#include <hip/hip_runtime.h>
#include <hip/hip_cooperative_groups.h>

namespace cg = cooperative_groups;

#define FDIM 1024
#define FD4 256   // dwords (quantized) / float4s per row
#define BDIM 512
#define PDIM 512

__device__ __forceinline__ unsigned sad8(unsigned a, unsigned b, unsigned c) {
  return __builtin_amdgcn_sad_u8(a, b, c);  // sum_{4 bytes} |a_i - b_i| + c
}

__device__ __forceinline__ unsigned quant4(float4 v) {
  float s0 = 1.f / (1.f + __expf(-v.x));
  float s1 = 1.f / (1.f + __expf(-v.y));
  float s2 = 1.f / (1.f + __expf(-v.z));
  float s3 = 1.f / (1.f + __expf(-v.w));
  unsigned q0 = (unsigned)(s0 * 255.f + 0.5f);
  unsigned q1 = (unsigned)(s1 * 255.f + 0.5f);
  unsigned q2 = (unsigned)(s2 * 255.f + 0.5f);
  unsigned q3 = (unsigned)(s3 * 255.f + 0.5f);
  return q0 | (q1 << 8) | (q2 << 16) | (q3 << 24);
}

// Single cooperative kernel, 512 blocks x 256 threads (2 blocks/CU).
// Phase 1 (balanced across ALL blocks, no tail):
//   - each block quantizes one w row -> wq (row-major), 1 float4/thread
//   - each block transpose-quantizes one 64-row x 4-dword x tile -> xqT,
//     via small padded LDS (conflict-free both directions), 1 float4/thread
// grid.sync() (device-scope fences -> cross-XCD visibility of ws)
// Phase 2 (the proven pair body): 64 b-rows (lane) x 8 p-cols per block;
//   4 waves split F (64 dwords each); x from transposed xqT (coalesced into
//   64 VGPRs), w via wave-uniform (scalar) loads.
__global__ __launch_bounds__(256) void tversky_coop(
    const float* __restrict__ x, const float* __restrict__ w,
    const float* __restrict__ bias, const float* __restrict__ alphap,
    const float* __restrict__ betap, float* __restrict__ out,
    unsigned* __restrict__ xqT, unsigned* __restrict__ wq) {
  __shared__ unsigned lt[64][5];        // 1.3 KB transpose staging
  __shared__ unsigned part[4][8][64];   // 8 KB
  __shared__ unsigned sxp[4][64];       // 1 KB
  __shared__ unsigned swsum[8];

  const int tid = threadIdx.x;
  const int blk = blockIdx.x;

  // ---- Phase 1a: quantize one w row (coalesced float4 per thread) ----
  {
    float4 v = ((const float4*)(w + (size_t)blk * FDIM))[tid];
    wq[blk * FD4 + tid] = quant4(v);
  }

  // ---- Phase 1b: transpose-quantize a 64x4-dword tile of x ----
  {
    const int rt = blk >> 6;            // 0..7  -> b-row tile
    const int ct = blk & 63;            // 0..63 -> dword-col tile
    const int r0 = rt * 64;
    const int d0 = ct * 4;
    const int row = tid >> 2;           // 0..63
    const int c = tid & 3;              // 0..3
    float4 v = ((const float4*)x)[(size_t)(r0 + row) * FD4 + d0 + c];
    lt[row][c] = quant4(v);
    __syncthreads();
    const int c2 = tid >> 6;            // 0..3   (wave-uniform)
    const int b = tid & 63;             // 0..63  (lane)
    xqT[(size_t)(d0 + c2) * BDIM + r0 + b] = lt[b][c2];
  }

  __threadfence();          // belt-and-braces release before grid barrier
  cg::this_grid().sync();   // device-scope: xqT/wq visible to all XCDs

  // ---- Phase 2: pair body (verbatim from the proven 70 us kernel) ----
  const int lane = tid & 63;
  const int wv = __builtin_amdgcn_readfirstlane(tid >> 6);  // F-slice, uniform
  const int bx = blk & 63;              // p tile (0..63)
  const int by = blk >> 6;              // b tile (0..7)
  const int r = by * 64 + lane;         // b row
  const int c0 = bx * 8;                // p col base

  if (tid < 8) swsum[tid] = 0;
  __syncthreads();

  // x slice: 64 coalesced dword loads (lane-contiguous in xqT).
  unsigned xv[64];
#pragma unroll
  for (int k = 0; k < 64; ++k) xv[k] = xqT[(wv * 64 + k) * BDIM + r];

  // Sx slice sum (sad vs 0 = byte sum).
  unsigned sx = 0;
#pragma unroll
  for (int k = 0; k < 64; ++k) sx = sad8(xv[k], 0u, sx);
  sxp[wv][lane] = sx;

  // Sw for this block's 8 w rows.
  {
    const int wrow = tid >> 5;
    const int seg = tid & 31;
    const unsigned* wp = wq + (c0 + wrow) * FD4 + seg * 8;
    unsigned s = 0;
#pragma unroll
    for (int j = 0; j < 8; ++j) s = sad8(wp[j], 0u, s);
    atomicAdd(&swsum[wrow], s);
  }

  // Main loop: 8 cols x 64 sads, 4 chains; w via uniform (scalar) loads.
  for (int pp = 0; pp < 8; ++pp) {
    const unsigned* wp = wq + (c0 + pp) * FD4 + wv * 64;
    unsigned a0 = 0, a1 = 0, a2 = 0, a3 = 0;
#pragma unroll
    for (int j = 0; j < 16; ++j) {
      a0 = sad8(xv[4 * j + 0], wp[4 * j + 0], a0);
      a1 = sad8(xv[4 * j + 1], wp[4 * j + 1], a1);
      a2 = sad8(xv[4 * j + 2], wp[4 * j + 2], a2);
      a3 = sad8(xv[4 * j + 3], wp[4 * j + 3], a3);
    }
    part[wv][pp][lane] = a0 + a1 + a2 + a3;
  }
  __syncthreads();

  const float alpha = alphap[0];
  const float beta = betap[0];
#pragma unroll
  for (int id = tid; id < 512; id += 256) {
    const int row = id >> 3;
    const int pp = id & 7;
    const unsigned D = part[0][pp][row] + part[1][pp][row] +
                       part[2][pp][row] + part[3][pp][row];
    const unsigned Sxi = sxp[0][row] + sxp[1][row] + sxp[2][row] + sxp[3][row];
    const unsigned Swi = swsum[pp];
    const int b = by * 64 + row;
    const int p = c0 + pp;
    const float fSx = (float)Sxi;
    const float fSw = (float)Swi;
    const float I = 0.5f * (fSx + fSw - (float)D);
    // All terms in int units (255x real); eps scales by 255.
    const float denom = I + alpha * (fSx - I) + beta * (fSw - I) + 255.0f * 1e-8f;
    out[b * PDIM + p] = I / denom + bias[p];
  }
}

extern "C" void kernel_launch(void* const* d_in, const int* in_sizes, int n_in,
                              void* d_out, int out_size, void* d_ws, size_t ws_size,
                              hipStream_t stream) {
  const float* x = (const float*)d_in[0];
  const float* w = (const float*)d_in[1];
  const float* bias = (const float*)d_in[2];
  const float* alpha = (const float*)d_in[3];
  const float* beta = (const float*)d_in[4];
  float* out = (float*)d_out;

  unsigned char* ws = (unsigned char*)d_ws;
  unsigned* xqT = (unsigned*)ws;                 // 512 KB, transposed [256][512]
  unsigned* wq = (unsigned*)(ws + 512 * 1024);   // 512 KB, row-major [512][256]
  (void)in_sizes; (void)n_in; (void)ws_size;

  void* args[] = {(void*)&x, (void*)&w, (void*)&bias, (void*)&alpha,
                  (void*)&beta, (void*)&out, (void*)&xqT, (void*)&wq};
  hipLaunchCooperativeKernel((void*)tversky_coop, dim3(512), dim3(256), args,
                             0, stream);
}

// Round 3
// 72.710 us; speedup vs baseline: 2.6445x; 2.6445x over previous
//
#include <hip/hip_runtime.h>

#define FDIM 1024
#define FD4 256   // dwords (quantized) / float4s per row
#define BDIM 512
#define PDIM 512

__device__ __forceinline__ unsigned sad8(unsigned a, unsigned b, unsigned c) {
  return __builtin_amdgcn_sad_u8(a, b, c);  // sum_{4 bytes} |a_i - b_i| + c
}

__device__ __forceinline__ unsigned quant4(float4 v) {
  float s0 = 1.f / (1.f + __expf(-v.x));
  float s1 = 1.f / (1.f + __expf(-v.y));
  float s2 = 1.f / (1.f + __expf(-v.z));
  float s3 = 1.f / (1.f + __expf(-v.w));
  unsigned q0 = (unsigned)(s0 * 255.f + 0.5f);
  unsigned q1 = (unsigned)(s1 * 255.f + 0.5f);
  unsigned q2 = (unsigned)(s2 * 255.f + 0.5f);
  unsigned q3 = (unsigned)(s3 * 255.f + 0.5f);
  return q0 | (q1 << 8) | (q2 << 16) | (q3 << 24);
}

// Kernel 1: transpose-quantize x only. 512 perfectly balanced blocks, each
// owns a 64-row x 4-dword tile: 1 float4 load + 4 sigmoids + 1 dword store
// per thread, through a tiny padded LDS tile (stride 5: worst 2-way bank
// aliasing, which is free on CDNA4).
__global__ __launch_bounds__(256) void xquant(const float* __restrict__ x,
                                              unsigned* __restrict__ xqT) {
  __shared__ unsigned lt[64][5];
  const int tid = threadIdx.x;
  const int blk = blockIdx.x;
  const int r0 = (blk >> 6) * 64;   // b-row base (8 row tiles)
  const int d0 = (blk & 63) * 4;    // dword-col base (64 col tiles)
  {
    const int row = tid >> 2;       // 0..63
    const int c = tid & 3;          // 0..3
    float4 v = ((const float4*)x)[(size_t)(r0 + row) * FD4 + d0 + c];
    lt[row][c] = quant4(v);
  }
  __syncthreads();
  {
    const int c2 = tid >> 6;        // 0..3  (wave-uniform)
    const int b = tid & 63;         // 0..63 (lane)
    xqT[(size_t)(d0 + c2) * BDIM + r0 + b] = lt[b][c2];
  }
}

// Kernel 2: 64 b-rows (lane) x 8 p-cols per block; 4 waves split F.
// Phase A: quantize this block's 8 w rows into LDS (8x redundant across
//          b-tiles; ~0.5 us chip-wide — removes non-scalarizing uniform
//          global loads AND the w half of kernel 1).
// Main loop: F in 4 chunks of 16 dwords; live set bounded by construction
//          (16 xv + 16 w + 8 acc + sx ~ 50-70 VGPR, no spill possible).
__global__ __launch_bounds__(256) void tversky_pair(
    const unsigned* __restrict__ xqT, const float* __restrict__ w,
    const float* __restrict__ bias, const float* __restrict__ alphap,
    const float* __restrict__ betap, float* __restrict__ out) {
  __shared__ __align__(16) unsigned wqs[8][FD4];   // 8 KB
  __shared__ unsigned short part[4][8][64];        // 4 KB (slice D <= 65280)
  __shared__ unsigned short sxp[4][64];            // 512 B (slice Sx <= 65280)
  __shared__ unsigned swsum[8];

  const int tid = threadIdx.x;
  const int lane = tid & 63;
  const int wv = __builtin_amdgcn_readfirstlane(tid >> 6);  // F-slice, uniform
  const int r = blockIdx.y * 64 + lane;  // b row
  const int c0 = blockIdx.x * 8;         // p col base

  if (tid < 8) swsum[tid] = 0;

  // Phase A: 8 w rows -> LDS (one full row per iter, coalesced).
  const float4* __restrict__ wf4 = (const float4*)w;
#pragma unroll
  for (int j = 0; j < 8; ++j) {
    wqs[j][tid] = quant4(wf4[(size_t)(c0 + j) * FD4 + tid]);
  }
  __syncthreads();

  // Sw for this block's 8 w rows (one-time; from LDS).
  {
    const int wrow = tid >> 5;
    const int seg = tid & 31;
    const uint4* wp = (const uint4*)&wqs[wrow][seg * 8];
    const uint4 q0 = wp[0], q1 = wp[1];
    unsigned s = 0;
    s = sad8(q0.x, 0u, s); s = sad8(q0.y, 0u, s);
    s = sad8(q0.z, 0u, s); s = sad8(q0.w, 0u, s);
    s = sad8(q1.x, 0u, s); s = sad8(q1.y, 0u, s);
    s = sad8(q1.z, 0u, s); s = sad8(q1.w, 0u, s);
    atomicAdd(&swsum[wrow], s);
  }

  // Main loop: 4 chunks of 16 dwords. Keep the chunk loop ROLLED so the
  // register footprint stays bounded (round-2 lesson: VGPR_Count=40 proved
  // the 64-reg xv design spills / re-loads).
  unsigned acc[8] = {0, 0, 0, 0, 0, 0, 0, 0};
  unsigned sx = 0;
#pragma unroll 1
  for (int c = 0; c < 4; ++c) {
    unsigned xv[16];
#pragma unroll
    for (int k = 0; k < 16; ++k)
      xv[k] = xqT[(size_t)(wv * 64 + c * 16 + k) * BDIM + r];
#pragma unroll
    for (int k = 0; k < 16; ++k) sx = sad8(xv[k], 0u, sx);
#pragma unroll
    for (int pp = 0; pp < 8; ++pp) {
      const uint4* qp = (const uint4*)&wqs[pp][wv * 64 + c * 16];
      const uint4 qa = qp[0], qb = qp[1], qc = qp[2], qd = qp[3];
      unsigned a = acc[pp];
      a = sad8(xv[0], qa.x, a);  a = sad8(xv[1], qa.y, a);
      a = sad8(xv[2], qa.z, a);  a = sad8(xv[3], qa.w, a);
      a = sad8(xv[4], qb.x, a);  a = sad8(xv[5], qb.y, a);
      a = sad8(xv[6], qb.z, a);  a = sad8(xv[7], qb.w, a);
      a = sad8(xv[8], qc.x, a);  a = sad8(xv[9], qc.y, a);
      a = sad8(xv[10], qc.z, a); a = sad8(xv[11], qc.w, a);
      a = sad8(xv[12], qd.x, a); a = sad8(xv[13], qd.y, a);
      a = sad8(xv[14], qd.z, a); a = sad8(xv[15], qd.w, a);
      acc[pp] = a;
    }
  }
  sxp[wv][lane] = (unsigned short)sx;
#pragma unroll
  for (int pp = 0; pp < 8; ++pp)
    part[wv][pp][lane] = (unsigned short)acc[pp];
  __syncthreads();

  // Epilogue: reduce 4 F-slices, Tversky ratio + bias.
  const float alpha = alphap[0];
  const float beta = betap[0];
#pragma unroll
  for (int id = tid; id < 512; id += 256) {
    const int row = id >> 3;
    const int pp = id & 7;
    const unsigned D = (unsigned)part[0][pp][row] + part[1][pp][row] +
                       part[2][pp][row] + part[3][pp][row];
    const unsigned Sxi = (unsigned)sxp[0][row] + sxp[1][row] +
                         sxp[2][row] + sxp[3][row];
    const unsigned Swi = swsum[pp];
    const float fSx = (float)Sxi;
    const float fSw = (float)Swi;
    const float I = 0.5f * (fSx + fSw - (float)D);
    // All terms in int units (255x real); eps scales by 255.
    const float denom = I + alpha * (fSx - I) + beta * (fSw - I) + 255.0f * 1e-8f;
    out[(blockIdx.y * 64 + row) * PDIM + (c0 + pp)] = I / denom + bias[c0 + pp];
  }
}

extern "C" void kernel_launch(void* const* d_in, const int* in_sizes, int n_in,
                              void* d_out, int out_size, void* d_ws, size_t ws_size,
                              hipStream_t stream) {
  const float* x = (const float*)d_in[0];
  const float* w = (const float*)d_in[1];
  const float* bias = (const float*)d_in[2];
  const float* alpha = (const float*)d_in[3];
  const float* beta = (const float*)d_in[4];
  float* out = (float*)d_out;

  unsigned* xqT = (unsigned*)d_ws;  // 512 KB, transposed [256][512]
  (void)in_sizes; (void)n_in; (void)ws_size;

  xquant<<<dim3(512), dim3(256), 0, stream>>>(x, xqT);
  tversky_pair<<<dim3(PDIM / 8, BDIM / 64), dim3(256), 0, stream>>>(
      xqT, w, bias, alpha, beta, out);
}